// Round 3
// baseline (2326.888 us; speedup 1.0000x reference)
//
#include <hip/hip_runtime.h>
#include <cstddef>

#define Bc   8
#define Cc   128
#define Hc   64
#define Wc   64
#define HWc  (Hc*Wc)
#define PADc 3

// ---------------------------------------------------------------------------
// Kernel A: attention gate.  att[b,h,w] = sigmoid( sum_c conv7(input)*a_w
//                                               + sum_c conv7(exc)*a_u + biases )
// block = 128 threads = 16x8 spatial tile; grid = (32 tiles, B) = 256 blocks
// ---------------------------------------------------------------------------
__global__ __launch_bounds__(128) void att_kernel(
    const float* __restrict__ input_, const float* __restrict__ exc,
    const float* __restrict__ aw, const float* __restrict__ au,
    const float* __restrict__ awb, const float* __restrict__ aub,
    float* __restrict__ att)
{
    __shared__ float wsa[Cc*49];
    __shared__ float wsb[Cc*49];
    __shared__ float ti[14*22];
    __shared__ float te[14*22];
    const int tid = threadIdx.x;
    for (int i = tid; i < Cc*49; i += 128) { wsa[i] = aw[i]; wsb[i] = au[i]; }
    const int tile = blockIdx.x, b = blockIdx.y;
    const int y0 = (tile >> 2) * 8, x0 = (tile & 3) * 16;
    const int tx = tid & 15, ty = tid >> 4;   // ty 0..7
    const float* ib = input_ + (size_t)b*Cc*HWc;
    const float* eb = exc    + (size_t)b*Cc*HWc;
    float acc = 0.f;
    for (int ci = 0; ci < Cc; ++ci) {
        __syncthreads();
        for (int i = tid; i < 14*22; i += 128) {
            int iy = i / 22, ix = i - iy*22;
            int gy = y0 + iy - PADc, gx = x0 + ix - PADc;
            float v0 = 0.f, v1 = 0.f;
            if (gy >= 0 && gy < Hc && gx >= 0 && gx < Wc) {
                size_t o = (size_t)ci*HWc + gy*Wc + gx;
                v0 = ib[o]; v1 = eb[o];
            }
            ti[i] = v0; te[i] = v1;
        }
        __syncthreads();
        const float* wa = &wsa[ci*49];
        const float* wb = &wsb[ci*49];
        #pragma unroll
        for (int kh = 0; kh < 7; ++kh) {
            #pragma unroll
            for (int kw = 0; kw < 7; ++kw) {
                const int k = kh*7+kw;
                acc += ti[(ty+kh)*22 + tx+kw] * wa[k];
                acc += te[(ty+kh)*22 + tx+kw] * wb[k];
            }
        }
    }
    float z = acc + awb[0] + aub[0];
    att[(size_t)b*HWc + (size_t)(y0+ty)*Wc + (x0+tx)] = 1.f/(1.f+expf(-z));
}

// ---------------------------------------------------------------------------
// Kernel B/F: 7x7 conv, 128->128 channels, optional broadcast gate on input.
// block = 256 threads; tile = 32x32 spatial x 8 c_out; 2x2 outputs/thread.
// grid = (4 spatial tiles, 16 c_out tiles, B) = 512 blocks (2 blocks/CU)
// ---------------------------------------------------------------------------
#define TS  32
#define TIN 38
#define COT 8

__global__ __launch_bounds__(256) void conv7_kernel(
    const float* __restrict__ x, const float* __restrict__ gate,
    const float* __restrict__ w, float* __restrict__ out)
{
    __shared__ float st[TIN*TIN];
    __shared__ float sw[49][COT];
    const int tid  = threadIdx.x;
    const int tile = blockIdx.x;
    const int cob  = blockIdx.y * COT;
    const int b    = blockIdx.z;
    const int y0 = (tile >> 1) * TS, x0 = (tile & 1) * TS;
    const int tx = (tid & 15) * 2, ty = (tid >> 4) * 2;

    float acc[COT*4];
    #pragma unroll
    for (int i = 0; i < COT*4; ++i) acc[i] = 0.f;

    const float* xb = x + (size_t)b*Cc*HWc;
    const float* gb = gate ? gate + (size_t)b*HWc : nullptr;

    for (int ci = 0; ci < Cc; ++ci) {
        __syncthreads();
        // stage input tile (with gate multiply + zero pad)
        for (int i = tid; i < TIN*TIN; i += 256) {
            int iy = i / TIN, ix = i - iy*TIN;
            int gy = y0 + iy - PADc, gx = x0 + ix - PADc;
            float v = 0.f;
            if (gy >= 0 && gy < Hc && gx >= 0 && gx < Wc) {
                v = xb[(size_t)ci*HWc + (size_t)gy*Wc + gx];
                if (gb) v *= gb[(size_t)gy*Wc + gx];
            }
            st[i] = v;
        }
        // stage weights: w[cob+co][ci][k] -> sw[k][co]
        for (int i = tid; i < 49*COT; i += 256) {
            int co = i / 49, k = i - co*49;
            sw[k][co] = w[((size_t)(cob+co)*Cc + ci)*49 + k];
        }
        __syncthreads();
        #pragma unroll
        for (int kh = 0; kh < 7; ++kh) {
            #pragma unroll
            for (int kw = 0; kw < 7; ++kw) {
                float g00 = st[(ty+kh  )*TIN + tx+kw  ];
                float g01 = st[(ty+kh  )*TIN + tx+kw+1];
                float g10 = st[(ty+kh+1)*TIN + tx+kw  ];
                float g11 = st[(ty+kh+1)*TIN + tx+kw+1];
                const int k = kh*7+kw;
                #pragma unroll
                for (int co = 0; co < COT; ++co) {
                    float wv = sw[k][co];
                    acc[co*4+0] += g00*wv;
                    acc[co*4+1] += g01*wv;
                    acc[co*4+2] += g10*wv;
                    acc[co*4+3] += g11*wv;
                }
            }
        }
    }
    #pragma unroll
    for (int co = 0; co < COT; ++co) {
        size_t base = ((size_t)b*Cc + cob+co)*HWc;
        out[base + (size_t)(y0+ty  )*Wc + tx+x0  ] = acc[co*4+0];
        out[base + (size_t)(y0+ty  )*Wc + tx+x0+1] = acc[co*4+1];
        out[base + (size_t)(y0+ty+1)*Wc + tx+x0  ] = acc[co*4+2];
        out[base + (size_t)(y0+ty+1)*Wc + tx+x0+1] = acc[co*4+3];
    }
}

// ---------------------------------------------------------------------------
// BN stats: one block per channel; folds BN to per-channel scale/bias:
//   intx = x*sc + bi
// ---------------------------------------------------------------------------
__global__ __launch_bounds__(256) void bn_stats_kernel(
    const float* __restrict__ x, const float* __restrict__ g,
    const float* __restrict__ bta, float* __restrict__ sc, float* __restrict__ bi)
{
    const int c = blockIdx.x;
    const int tid = threadIdx.x;
    float s = 0.f, s2 = 0.f;
    for (int i = tid; i < Bc*HWc; i += 256) {
        int b = i >> 12;          // HWc = 4096
        int p = i & (HWc-1);
        float v = x[((size_t)b*Cc + c)*HWc + p];
        s += v; s2 += v*v;
    }
    #pragma unroll
    for (int off = 32; off > 0; off >>= 1) {
        s  += __shfl_down(s,  off);
        s2 += __shfl_down(s2, off);
    }
    __shared__ float ls[4], ls2[4];
    const int wv = tid >> 6;
    if ((tid & 63) == 0) { ls[wv] = s; ls2[wv] = s2; }
    __syncthreads();
    if (tid == 0) {
        s  = ls[0]+ls[1]+ls[2]+ls[3];
        s2 = ls2[0]+ls2[1]+ls2[2]+ls2[3];
        const float n = (float)(Bc*HWc);
        float m   = s / n;
        float var = s2 / n - m*m;
        float r   = rsqrtf(var + 1e-3f);
        float scale = r * g[c];
        sc[c] = scale;
        bi[c] = bta[c] - m*scale;
    }
}

// ---------------------------------------------------------------------------
// Kernel E: i-gate 1x1 convs + inhibition_hat + state update (fused).
// Reads c1 (conv+BN input) from d_out first half and overwrites it in place
// with the new inhibition.  block = 256 pixels; 32 c_out per block.
// grid = (HW/256, C/32, B) = 512 blocks
// ---------------------------------------------------------------------------
#define GCO 32

__global__ __launch_bounds__(256) void gate_i_kernel(
    const float* __restrict__ input_, const float* __restrict__ inh,
    const float* __restrict__ iw, const float* __restrict__ iwb,
    const float* __restrict__ uw, const float* __restrict__ uwb,
    const float* c1, const float* __restrict__ sc, const float* __restrict__ bi,
    const float* __restrict__ att,
    const float* __restrict__ alpha, const float* __restrict__ mu,
    float* out)
{
    __shared__ float swi[Cc][GCO];
    __shared__ float swu[Cc][GCO];
    const int tid = threadIdx.x;
    const int p0  = blockIdx.x * 256;
    const int cob = blockIdx.y * GCO;
    const int b   = blockIdx.z;
    for (int i = tid; i < Cc*GCO; i += 256) {
        int ci = i / GCO, co = i % GCO;
        swi[ci][co] = iw[(size_t)(cob+co)*Cc + ci];
        swu[ci][co] = uw[(size_t)(cob+co)*Cc + ci];
    }
    __syncthreads();
    const int p = p0 + tid;
    const float* xb = input_ + (size_t)b*Cc*HWc + p;
    const float* hb = inh    + (size_t)b*Cc*HWc + p;
    float acc[GCO];
    #pragma unroll
    for (int i = 0; i < GCO; ++i) acc[i] = 0.f;
    for (int ci = 0; ci < Cc; ++ci) {
        float xi = xb[(size_t)ci*HWc];
        float xu = hb[(size_t)ci*HWc];
        #pragma unroll
        for (int co = 0; co < GCO; ++co)
            acc[co] += xi*swi[ci][co] + xu*swu[ci][co];
    }
    const float a = att[(size_t)b*HWc + p];
    #pragma unroll
    for (int co = 0; co < GCO; ++co) {
        const int c = cob + co;
        float hv = hb[(size_t)c*HWc];
        float g  = 1.f/(1.f+expf(-(acc[co] + iwb[c] + uwb[c])));
        size_t idx = ((size_t)b*Cc + c)*HWc + p;
        float intx = c1[idx]*sc[c] + bi[c];
        float gi = xb[(size_t)c*HWc] * a;
        float gh = hv * a;
        float ihat = tanhf(gi - tanhf(intx*(alpha[c]*gh + mu[c])));
        out[idx] = (1.f-g)*hv + g*ihat;
    }
}

// ---------------------------------------------------------------------------
// Kernel H: e-gate 1x1 convs + excitation_hat + state update (fused).
// Reads c2 from d_out second half and overwrites it in place.
// ---------------------------------------------------------------------------
__global__ __launch_bounds__(256) void gate_e_kernel(
    const float* __restrict__ inh_new, const float* __restrict__ exc,
    const float* __restrict__ ew, const float* __restrict__ ewb,
    const float* __restrict__ uw, const float* __restrict__ uwb,
    const float* c2, const float* __restrict__ sc, const float* __restrict__ bi,
    const float* __restrict__ kappa, const float* __restrict__ gamma_,
    const float* __restrict__ wp,
    float* out)
{
    __shared__ float swe[Cc][GCO];
    __shared__ float swu[Cc][GCO];
    const int tid = threadIdx.x;
    const int p0  = blockIdx.x * 256;
    const int cob = blockIdx.y * GCO;
    const int b   = blockIdx.z;
    for (int i = tid; i < Cc*GCO; i += 256) {
        int ci = i / GCO, co = i % GCO;
        swe[ci][co] = ew[(size_t)(cob+co)*Cc + ci];
        swu[ci][co] = uw[(size_t)(cob+co)*Cc + ci];
    }
    __syncthreads();
    const int p = p0 + tid;
    const float* hb = inh_new + (size_t)b*Cc*HWc + p;  // new inhibition
    const float* eb = exc     + (size_t)b*Cc*HWc + p;  // original excitation
    float acc[GCO];
    #pragma unroll
    for (int i = 0; i < GCO; ++i) acc[i] = 0.f;
    for (int ci = 0; ci < Cc; ++ci) {
        float xi = hb[(size_t)ci*HWc];
        float xu = eb[(size_t)ci*HWc];
        #pragma unroll
        for (int co = 0; co < GCO; ++co)
            acc[co] += xi*swe[ci][co] + xu*swu[ci][co];
    }
    #pragma unroll
    for (int co = 0; co < GCO; ++co) {
        const int c = cob + co;
        float hv = hb[(size_t)c*HWc];
        float ev = eb[(size_t)c*HWc];
        float g  = 1.f/(1.f+expf(-(acc[co] + ewb[c] + uwb[c])));
        size_t idx = ((size_t)b*Cc + c)*HWc + p;
        float intx = c2[idx]*sc[c] + bi[c];
        float ehat = tanhf(kappa[c]*hv + gamma_[c]*intx + wp[c]*hv*intx);
        out[idx] = (1.f-g)*ev + g*ehat;
    }
}

// ---------------------------------------------------------------------------
extern "C" void kernel_launch(void* const* d_in, const int* in_sizes, int n_in,
                              void* d_out, int out_size, void* d_ws, size_t ws_size,
                              hipStream_t stream)
{
    (void)in_sizes; (void)n_in; (void)out_size; (void)ws_size;
    const float* input_ = (const float*)d_in[0];
    const float* inh    = (const float*)d_in[1];
    const float* exc    = (const float*)d_in[2];
    const float* a_w_w  = (const float*)d_in[3];
    const float* a_w_b  = (const float*)d_in[4];
    const float* a_u_w  = (const float*)d_in[5];
    const float* a_u_b  = (const float*)d_in[6];
    const float* i_w_w  = (const float*)d_in[7];
    const float* i_w_b  = (const float*)d_in[8];
    const float* i_u_w  = (const float*)d_in[9];
    const float* i_u_b  = (const float*)d_in[10];
    const float* e_w_w  = (const float*)d_in[11];
    const float* e_w_b  = (const float*)d_in[12];
    const float* e_u_w  = (const float*)d_in[13];
    const float* e_u_b  = (const float*)d_in[14];
    const float* w_inh  = (const float*)d_in[15];
    const float* w_exc  = (const float*)d_in[16];
    const float* alpha  = (const float*)d_in[17];
    const float* gamma_ = (const float*)d_in[18];
    const float* kappa  = (const float*)d_in[19];
    const float* w_par  = (const float*)d_in[20];
    const float* mu     = (const float*)d_in[21];
    const float* bn0_g  = (const float*)d_in[22];
    const float* bn0_b  = (const float*)d_in[23];
    const float* bn1_g  = (const float*)d_in[24];
    const float* bn1_b  = (const float*)d_in[25];

    float* out = (float*)d_out;
    const size_t N = (size_t)Bc*Cc*HWc;
    float* c1 = out;        // conv1 output lives in d_out[0..N), overwritten in place
    float* c2 = out + N;    // conv2 output lives in d_out[N..2N), overwritten in place

    float* att = (float*)d_ws;          // B*HW floats
    float* sc0 = att + (size_t)Bc*HWc;  // 128
    float* bi0 = sc0 + Cc;
    float* sc1 = bi0 + Cc;
    float* bi1 = sc1 + Cc;

    // 1. attention gate
    att_kernel<<<dim3(32, Bc), 128, 0, stream>>>(input_, exc, a_w_w, a_u_w, a_w_b, a_u_b, att);
    // 2. conv(excitation * att, w_inh) -> c1
    conv7_kernel<<<dim3(4, Cc/COT, Bc), 256, 0, stream>>>(exc, att, w_inh, c1);
    // 3. BN stats for c1
    bn_stats_kernel<<<Cc, 256, 0, stream>>>(c1, bn0_g, bn0_b, sc0, bi0);
    // 4. i-gate + inhibition_hat + update -> inhibition_new (in place over c1)
    gate_i_kernel<<<dim3(HWc/256, Cc/GCO, Bc), 256, 0, stream>>>(
        input_, inh, i_w_w, i_w_b, i_u_w, i_u_b, c1, sc0, bi0, att, alpha, mu, out);
    // 5. conv(inhibition_new, w_exc) -> c2
    conv7_kernel<<<dim3(4, Cc/COT, Bc), 256, 0, stream>>>(out, nullptr, w_exc, c2);
    // 6. BN stats for c2
    bn_stats_kernel<<<Cc, 256, 0, stream>>>(c2, bn1_g, bn1_b, sc1, bi1);
    // 7. e-gate + excitation_hat + update -> excitation_new (in place over c2)
    gate_e_kernel<<<dim3(HWc/256, Cc/GCO, Bc), 256, 0, stream>>>(
        out, exc, e_w_w, e_w_b, e_u_w, e_u_b, c2, sc1, bi1, kappa, gamma_, w_par, out + N);
}

// Round 4
// 804.028 us; speedup vs baseline: 2.8940x; 2.8940x over previous
//
#include <hip/hip_runtime.h>
#include <cstddef>

typedef _Float16 f16;
typedef _Float16 f16x8 __attribute__((ext_vector_type(8)));
typedef float f32x16 __attribute__((ext_vector_type(16)));

#define Bc   8
#define Cc   128
#define Hc   64
#define Wc   64
#define HWc  4096
#define PADc 3
#define TAPS 49

// ---------------- conv7 MFMA geometry ----------------
#define PY 8            // output rows per workgroup
#define PX 16           // output cols per workgroup
#define WY 14           // input window rows  (PY+6)
#define WX 22           // input window cols  (PX+6)
#define NPOS (WY*WX)    // 308 staged positions
#define AROW 256        // bytes per position row (128 ci * 2B)
#define ALDS_BYTES (NPOS*AROW)        // 78848
#define WBUF_BYTES (Cc*Cc*2)          // 32768 (one tap, f16)

// ---------------------------------------------------------------------------
// prep: transpose both conv weights to [tap][co][ci] f16, zero att buffer
// ---------------------------------------------------------------------------
__global__ __launch_bounds__(256) void prep_kernel(
    const float* __restrict__ w1, const float* __restrict__ w2,
    f16* __restrict__ wt1, f16* __restrict__ wt2, float* __restrict__ att)
{
    int idx = blockIdx.x*256 + threadIdx.x;
    const int NW = TAPS*Cc*Cc;
    if (idx < NW) {
        int tap = idx / (Cc*Cc);
        int rem = idx - tap*(Cc*Cc);
        int co = rem >> 7, ci = rem & 127;
        size_t src = (size_t)(co*Cc + ci)*TAPS + tap;
        wt1[idx] = (f16)w1[src];
        wt2[idx] = (f16)w2[src];
    }
    if (idx < Bc*HWc) att[idx] = 0.f;
}

// ---------------------------------------------------------------------------
// attention gate, ci-split partial sums (atomicAdd), then sigmoid finalize
// ---------------------------------------------------------------------------
__global__ __launch_bounds__(128) void att_partial(
    const float* __restrict__ input_, const float* __restrict__ exc,
    const float* __restrict__ aw, const float* __restrict__ au,
    float* __restrict__ att)
{
    __shared__ float wsa[32*49];
    __shared__ float wsb[32*49];
    __shared__ float ti[WY*WX];
    __shared__ float te[WY*WX];
    const int tid = threadIdx.x;
    const int tile = blockIdx.x;          // 0..31
    const int cch  = blockIdx.y*32;       // ci chunk base
    const int b    = blockIdx.z;
    for (int i = tid; i < 32*49; i += 128) { wsa[i] = aw[cch*49 + i]; wsb[i] = au[cch*49 + i]; }
    const int y0 = (tile >> 2)*8, x0 = (tile & 3)*16;
    const int tx = tid & 15, ty = tid >> 4;   // ty 0..7
    const float* ib = input_ + (size_t)b*Cc*HWc;
    const float* eb = exc    + (size_t)b*Cc*HWc;
    float acc = 0.f;
    for (int ci = 0; ci < 32; ++ci) {
        __syncthreads();
        for (int i = tid; i < WY*WX; i += 128) {
            int iy = i / WX, ix = i - iy*WX;
            int gy = y0 + iy - PADc, gx = x0 + ix - PADc;
            float v0 = 0.f, v1 = 0.f;
            if (gy >= 0 && gy < Hc && gx >= 0 && gx < Wc) {
                size_t o = (size_t)(cch+ci)*HWc + gy*Wc + gx;
                v0 = ib[o]; v1 = eb[o];
            }
            ti[i] = v0; te[i] = v1;
        }
        __syncthreads();
        const float* wa = &wsa[ci*49];
        const float* wb = &wsb[ci*49];
        #pragma unroll
        for (int kh = 0; kh < 7; ++kh) {
            #pragma unroll
            for (int kw = 0; kw < 7; ++kw) {
                const int k = kh*7+kw;
                acc += ti[(ty+kh)*WX + tx+kw] * wa[k];
                acc += te[(ty+kh)*WX + tx+kw] * wb[k];
            }
        }
    }
    atomicAdd(&att[(size_t)b*HWc + (size_t)(y0+ty)*Wc + (x0+tx)], acc);
}

__global__ __launch_bounds__(256) void att_final(
    float* __restrict__ att, const float* __restrict__ awb, const float* __restrict__ aub)
{
    int i = blockIdx.x*256 + threadIdx.x;
    float z = att[i] + awb[0] + aub[0];
    att[i] = 1.f/(1.f+expf(-z));
}

// ---------------------------------------------------------------------------
// conv7 via MFMA implicit GEMM.
// A = weights (M=co=128), B = activations (N=px=128: 8 rows x 16 cols), K = ci.
// 4 waves (2 co-halves x 2 px-halves), wave tile 64co x 64px = 2x2 MFMA 32x32.
// Activations staged once in XOR-swizzled f16 LDS; weights [tap][co][ci]
// double-buffered per tap with register prefetch.
// grid = (4 x-tiles, 8 y-tiles, B) = 256 blocks, 256 threads.
// ---------------------------------------------------------------------------
__global__ __launch_bounds__(256) void conv7_mfma(
    const float* __restrict__ x, const float* __restrict__ att,
    const f16* __restrict__ wt, float* __restrict__ out)
{
    __shared__ unsigned char smem[ALDS_BYTES + 2*WBUF_BYTES];
    const int tid = threadIdx.x;
    const int x0 = blockIdx.x * PX;
    const int y0 = blockIdx.y * PY;
    const int b  = blockIdx.z;
    const float* xb = x + (size_t)b*Cc*HWc;

    // ---- stage activations: [pos][ci] f16, slot-swizzled ----
    for (int idx = tid; idx < NPOS*16; idx += 256) {
        int slot = idx / NPOS;            // 16B slot = 8 ci
        int pos  = idx - slot*NPOS;
        int r = pos / WX, xw = pos - r*WX;
        int gy = y0 + r - PADc, gx = x0 + xw - PADc;
        bool inb = (gy >= 0 && gy < Hc && gx >= 0 && gx < Wc);
        float g = 1.f;
        if (att) g = inb ? att[(size_t)b*HWc + gy*Wc + gx] : 0.f;
        unsigned int pk[4];
        #pragma unroll
        for (int jj = 0; jj < 4; ++jj) {
            float v0 = 0.f, v1 = 0.f;
            if (inb) {
                size_t o = (size_t)(slot*8 + jj*2)*HWc + (size_t)gy*Wc + gx;
                v0 = xb[o]; v1 = xb[o + HWc];
            }
            f16 h0 = (f16)(v0*g), h1 = (f16)(v1*g);
            unsigned short u0 = __builtin_bit_cast(unsigned short, h0);
            unsigned short u1 = __builtin_bit_cast(unsigned short, h1);
            pk[jj] = (unsigned int)u0 | ((unsigned int)u1 << 16);
        }
        *(uint4*)(smem + pos*AROW + ((slot ^ (pos & 15)) << 4)) =
            make_uint4(pk[0], pk[1], pk[2], pk[3]);
    }

    // ---- stage weights tap 0 into wbuf[0] ----
    {
        const uint4* src = (const uint4*)wt;
        #pragma unroll
        for (int ro = 0; ro < 8; ++ro) {
            int gidx = tid + ro*256;
            uint4 v = src[gidx];
            int co = gidx >> 4, slot = gidx & 15;
            *(uint4*)(smem + ALDS_BYTES + (co << 8) + ((slot ^ (co & 15)) << 4)) = v;
        }
    }
    __syncthreads();

    const int l   = tid & 63;
    const int wid = tid >> 6;
    const int wco = (wid >> 1) << 6;       // 0 / 64
    const int wpy = (wid & 1) << 2;        // 0 / 4
    const int lr  = l & 31;
    const int hi  = l >> 5;                // 0/1
    const int yA  = wpy + (lr >> 4);       // local row for nt=0
    const int xA  = lr & 15;

    f32x16 acc00 = {}, acc01 = {}, acc10 = {}, acc11 = {};
    uint4 w8[8];
    int cur = 0;

    for (int t = 0; t < TAPS; ++t) {
        if (t < TAPS-1) {
            const uint4* src = (const uint4*)(wt + (size_t)(t+1)*Cc*Cc);
            #pragma unroll
            for (int ro = 0; ro < 8; ++ro) w8[ro] = src[tid + ro*256];
        }
        const unsigned char* wb = smem + ALDS_BYTES + cur*WBUF_BYTES;
        const int kh = t / 7, kw = t - kh*7;
        const int pos0 = (yA + kh)*WX + xA + kw;
        const int pos1 = pos0 + 2*WX;
        #pragma unroll
        for (int s = 0; s < 8; ++s) {
            const int slot = (s << 1) + hi;
            const int swzW = (slot ^ xA) << 4;
            f16x8 a0 = *(const f16x8*)(wb + ((wco      + lr) << 8) + swzW);
            f16x8 a1 = *(const f16x8*)(wb + ((wco + 32 + lr) << 8) + swzW);
            f16x8 b0 = *(const f16x8*)(smem + pos0*AROW + ((slot ^ (pos0 & 15)) << 4));
            f16x8 b1 = *(const f16x8*)(smem + pos1*AROW + ((slot ^ (pos1 & 15)) << 4));
            acc00 = __builtin_amdgcn_mfma_f32_32x32x16_f16(a0, b0, acc00, 0, 0, 0);
            acc01 = __builtin_amdgcn_mfma_f32_32x32x16_f16(a0, b1, acc01, 0, 0, 0);
            acc10 = __builtin_amdgcn_mfma_f32_32x32x16_f16(a1, b0, acc10, 0, 0, 0);
            acc11 = __builtin_amdgcn_mfma_f32_32x32x16_f16(a1, b1, acc11, 0, 0, 0);
        }
        if (t < TAPS-1) {
            __syncthreads();
            unsigned char* wdst = smem + ALDS_BYTES + (cur^1)*WBUF_BYTES;
            #pragma unroll
            for (int ro = 0; ro < 8; ++ro) {
                int gidx = tid + ro*256;
                int co = gidx >> 4, slot = gidx & 15;
                *(uint4*)(wdst + (co << 8) + ((slot ^ (co & 15)) << 4)) = w8[ro];
            }
            __syncthreads();
            cur ^= 1;
        }
    }

    // ---- epilogue: C row = co, col = px ----
    const int xg = x0 + xA;
    #pragma unroll
    for (int r = 0; r < 16; ++r) {
        const int cr = (r & 3) + 8*(r >> 2) + 4*hi;
        const int y00 = y0 + wpy + 0 + (lr >> 4);
        const int y01 = y0 + wpy + 2 + (lr >> 4);
        out[((size_t)b*Cc + wco      + cr)*HWc + (size_t)y00*Wc + xg] = acc00[r];
        out[((size_t)b*Cc + wco      + cr)*HWc + (size_t)y01*Wc + xg] = acc01[r];
        out[((size_t)b*Cc + wco + 32 + cr)*HWc + (size_t)y00*Wc + xg] = acc10[r];
        out[((size_t)b*Cc + wco + 32 + cr)*HWc + (size_t)y01*Wc + xg] = acc11[r];
    }
}

// ---------------------------------------------------------------------------
// BN stats -> per-channel scale/bias
// ---------------------------------------------------------------------------
__global__ __launch_bounds__(256) void bn_stats_kernel(
    const float* __restrict__ x, const float* __restrict__ g,
    const float* __restrict__ bta, float* __restrict__ sc, float* __restrict__ bi)
{
    const int c = blockIdx.x;
    const int tid = threadIdx.x;
    float s = 0.f, s2 = 0.f;
    for (int i = tid; i < Bc*HWc; i += 256) {
        int b = i >> 12;
        int p = i & (HWc-1);
        float v = x[((size_t)b*Cc + c)*HWc + p];
        s += v; s2 += v*v;
    }
    #pragma unroll
    for (int off = 32; off > 0; off >>= 1) {
        s  += __shfl_down(s,  off);
        s2 += __shfl_down(s2, off);
    }
    __shared__ float ls[4], ls2[4];
    const int wv = tid >> 6;
    if ((tid & 63) == 0) { ls[wv] = s; ls2[wv] = s2; }
    __syncthreads();
    if (tid == 0) {
        s  = ls[0]+ls[1]+ls[2]+ls[3];
        s2 = ls2[0]+ls2[1]+ls2[2]+ls2[3];
        const float n = (float)(Bc*HWc);
        float m   = s / n;
        float var = s2 / n - m*m;
        float r   = rsqrtf(var + 1e-3f);
        float scale = r * g[c];
        sc[c] = scale;
        bi[c] = bta[c] - m*scale;
    }
}

// ---------------------------------------------------------------------------
// i-gate 1x1 convs + inhibition_hat + state update (fused)
// ---------------------------------------------------------------------------
#define GCO 32

__global__ __launch_bounds__(256) void gate_i_kernel(
    const float* __restrict__ input_, const float* __restrict__ inh,
    const float* __restrict__ iw, const float* __restrict__ iwb,
    const float* __restrict__ uw, const float* __restrict__ uwb,
    const float* c1, const float* __restrict__ sc, const float* __restrict__ bi,
    const float* __restrict__ att,
    const float* __restrict__ alpha, const float* __restrict__ mu,
    float* out)
{
    __shared__ float swi[Cc][GCO];
    __shared__ float swu[Cc][GCO];
    const int tid = threadIdx.x;
    const int p0  = blockIdx.x * 256;
    const int cob = blockIdx.y * GCO;
    const int b   = blockIdx.z;
    for (int i = tid; i < Cc*GCO; i += 256) {
        int ci = i / GCO, co = i % GCO;
        swi[ci][co] = iw[(size_t)(cob+co)*Cc + ci];
        swu[ci][co] = uw[(size_t)(cob+co)*Cc + ci];
    }
    __syncthreads();
    const int p = p0 + tid;
    const float* xb = input_ + (size_t)b*Cc*HWc + p;
    const float* hb = inh    + (size_t)b*Cc*HWc + p;
    float acc[GCO];
    #pragma unroll
    for (int i = 0; i < GCO; ++i) acc[i] = 0.f;
    for (int ci = 0; ci < Cc; ++ci) {
        float xi = xb[(size_t)ci*HWc];
        float xu = hb[(size_t)ci*HWc];
        #pragma unroll
        for (int co = 0; co < GCO; ++co)
            acc[co] += xi*swi[ci][co] + xu*swu[ci][co];
    }
    const float a = att[(size_t)b*HWc + p];
    #pragma unroll
    for (int co = 0; co < GCO; ++co) {
        const int c = cob + co;
        float hv = hb[(size_t)c*HWc];
        float g  = 1.f/(1.f+expf(-(acc[co] + iwb[c] + uwb[c])));
        size_t idx = ((size_t)b*Cc + c)*HWc + p;
        float intx = c1[idx]*sc[c] + bi[c];
        float gi = xb[(size_t)c*HWc] * a;
        float gh = hv * a;
        float ihat = tanhf(gi - tanhf(intx*(alpha[c]*gh + mu[c])));
        out[idx] = (1.f-g)*hv + g*ihat;
    }
}

// ---------------------------------------------------------------------------
// e-gate 1x1 convs + excitation_hat + state update (fused)
// ---------------------------------------------------------------------------
__global__ __launch_bounds__(256) void gate_e_kernel(
    const float* __restrict__ inh_new, const float* __restrict__ exc,
    const float* __restrict__ ew, const float* __restrict__ ewb,
    const float* __restrict__ uw, const float* __restrict__ uwb,
    const float* c2, const float* __restrict__ sc, const float* __restrict__ bi,
    const float* __restrict__ kappa, const float* __restrict__ gamma_,
    const float* __restrict__ wp,
    float* out)
{
    __shared__ float swe[Cc][GCO];
    __shared__ float swu[Cc][GCO];
    const int tid = threadIdx.x;
    const int p0  = blockIdx.x * 256;
    const int cob = blockIdx.y * GCO;
    const int b   = blockIdx.z;
    for (int i = tid; i < Cc*GCO; i += 256) {
        int ci = i / GCO, co = i % GCO;
        swe[ci][co] = ew[(size_t)(cob+co)*Cc + ci];
        swu[ci][co] = uw[(size_t)(cob+co)*Cc + ci];
    }
    __syncthreads();
    const int p = p0 + tid;
    const float* hb = inh_new + (size_t)b*Cc*HWc + p;
    const float* eb = exc     + (size_t)b*Cc*HWc + p;
    float acc[GCO];
    #pragma unroll
    for (int i = 0; i < GCO; ++i) acc[i] = 0.f;
    for (int ci = 0; ci < Cc; ++ci) {
        float xi = hb[(size_t)ci*HWc];
        float xu = eb[(size_t)ci*HWc];
        #pragma unroll
        for (int co = 0; co < GCO; ++co)
            acc[co] += xi*swe[ci][co] + xu*swu[ci][co];
    }
    #pragma unroll
    for (int co = 0; co < GCO; ++co) {
        const int c = cob + co;
        float hv = hb[(size_t)c*HWc];
        float ev = eb[(size_t)c*HWc];
        float g  = 1.f/(1.f+expf(-(acc[co] + ewb[c] + uwb[c])));
        size_t idx = ((size_t)b*Cc + c)*HWc + p;
        float intx = c2[idx]*sc[c] + bi[c];
        float ehat = tanhf(kappa[c]*hv + gamma_[c]*intx + wp[c]*hv*intx);
        out[idx] = (1.f-g)*ev + g*ehat;
    }
}

// ---------------------------------------------------------------------------
extern "C" void kernel_launch(void* const* d_in, const int* in_sizes, int n_in,
                              void* d_out, int out_size, void* d_ws, size_t ws_size,
                              hipStream_t stream)
{
    (void)in_sizes; (void)n_in; (void)out_size; (void)ws_size;
    const float* input_ = (const float*)d_in[0];
    const float* inh    = (const float*)d_in[1];
    const float* exc    = (const float*)d_in[2];
    const float* a_w_w  = (const float*)d_in[3];
    const float* a_w_b  = (const float*)d_in[4];
    const float* a_u_w  = (const float*)d_in[5];
    const float* a_u_b  = (const float*)d_in[6];
    const float* i_w_w  = (const float*)d_in[7];
    const float* i_w_b  = (const float*)d_in[8];
    const float* i_u_w  = (const float*)d_in[9];
    const float* i_u_b  = (const float*)d_in[10];
    const float* e_w_w  = (const float*)d_in[11];
    const float* e_w_b  = (const float*)d_in[12];
    const float* e_u_w  = (const float*)d_in[13];
    const float* e_u_b  = (const float*)d_in[14];
    const float* w_inh  = (const float*)d_in[15];
    const float* w_exc  = (const float*)d_in[16];
    const float* alpha  = (const float*)d_in[17];
    const float* gamma_ = (const float*)d_in[18];
    const float* kappa  = (const float*)d_in[19];
    const float* w_par  = (const float*)d_in[20];
    const float* mu     = (const float*)d_in[21];
    const float* bn0_g  = (const float*)d_in[22];
    const float* bn0_b  = (const float*)d_in[23];
    const float* bn1_g  = (const float*)d_in[24];
    const float* bn1_b  = (const float*)d_in[25];

    float* out = (float*)d_out;
    const size_t N = (size_t)Bc*Cc*HWc;
    float* c1 = out;
    float* c2 = out + N;

    float* att = (float*)d_ws;               // 32768 floats
    float* sc0 = att + 32768;
    float* bi0 = sc0 + Cc;
    float* sc1 = bi0 + Cc;
    float* bi1 = sc1 + Cc;
    f16* wt1 = (f16*)((char*)d_ws + 33280u*4u);       // 802816 f16
    f16* wt2 = wt1 + (size_t)TAPS*Cc*Cc;

    // 0. weight transpose (f16) + zero att
    prep_kernel<<<(TAPS*Cc*Cc + 255)/256, 256, 0, stream>>>(w_inh, w_exc, wt1, wt2, att);
    // 1. attention gate (ci-split partials + finalize)
    att_partial<<<dim3(32, 4, Bc), 128, 0, stream>>>(input_, exc, a_w_w, a_u_w, att);
    att_final<<<(Bc*HWc)/256, 256, 0, stream>>>(att, a_w_b, a_u_b);
    // 2. conv(exc * att, w_inh) -> c1  (MFMA)
    conv7_mfma<<<dim3(4, 8, Bc), 256, 0, stream>>>(exc, att, wt1, c1);
    // 3. BN stats for c1
    bn_stats_kernel<<<Cc, 256, 0, stream>>>(c1, bn0_g, bn0_b, sc0, bi0);
    // 4. i-gate + inhibition_hat + update -> inhibition_new (in place over c1)
    gate_i_kernel<<<dim3(HWc/256, Cc/GCO, Bc), 256, 0, stream>>>(
        input_, inh, i_w_w, i_w_b, i_u_w, i_u_b, c1, sc0, bi0, att, alpha, mu, out);
    // 5. conv(inhibition_new, w_exc) -> c2  (MFMA)
    conv7_mfma<<<dim3(4, 8, Bc), 256, 0, stream>>>(out, nullptr, wt2, c2);
    // 6. BN stats for c2
    bn_stats_kernel<<<Cc, 256, 0, stream>>>(c2, bn1_g, bn1_b, sc1, bi1);
    // 7. e-gate + excitation_hat + update -> excitation_new (in place over c2)
    gate_e_kernel<<<dim3(HWc/256, Cc/GCO, Bc), 256, 0, stream>>>(
        out, exc, e_w_w, e_w_b, e_u_w, e_u_b, c2, sc1, bi1, kappa, gamma_, w_par, out + N);
}

// Round 5
// 786.602 us; speedup vs baseline: 2.9582x; 1.0222x over previous
//
#include <hip/hip_runtime.h>
#include <cstddef>

typedef _Float16 f16;
typedef _Float16 f16x8 __attribute__((ext_vector_type(8)));
typedef float f32x16 __attribute__((ext_vector_type(16)));

#define Bc   8
#define Cc   128
#define Hc   64
#define Wc   64
#define HWc  4096
#define PADc 3
#define TAPS 49

// ---------------- conv7 MFMA geometry ----------------
#define PY 8            // output rows per workgroup
#define PX 16           // output cols per workgroup
#define WY 14           // input window rows  (PY+6)
#define WX 22           // input window cols  (PX+6)
#define NPOS (WY*WX)    // 308 staged positions
#define AROW 256        // bytes per position row (128 ci * 2B)
#define ALDS_BYTES (NPOS*AROW)        // 78848

// ---------------------------------------------------------------------------
// prep: transpose both conv weights to [tap][co][ci] f16, zero att buffer
// ---------------------------------------------------------------------------
__global__ __launch_bounds__(256) void prep_kernel(
    const float* __restrict__ w1, const float* __restrict__ w2,
    f16* __restrict__ wt1, f16* __restrict__ wt2, float* __restrict__ att)
{
    int idx = blockIdx.x*256 + threadIdx.x;
    const int NW = TAPS*Cc*Cc;
    if (idx < NW) {
        int tap = idx / (Cc*Cc);
        int rem = idx - tap*(Cc*Cc);
        int co = rem >> 7, ci = rem & 127;
        size_t src = (size_t)(co*Cc + ci)*TAPS + tap;
        wt1[idx] = (f16)w1[src];
        wt2[idx] = (f16)w2[src];
    }
    if (idx < Bc*HWc) att[idx] = 0.f;
}

// ---------------------------------------------------------------------------
// attention gate, ci-split partial sums (atomicAdd), then sigmoid finalize
// ---------------------------------------------------------------------------
__global__ __launch_bounds__(128) void att_partial(
    const float* __restrict__ input_, const float* __restrict__ exc,
    const float* __restrict__ aw, const float* __restrict__ au,
    float* __restrict__ att)
{
    __shared__ float wsa[32*49];
    __shared__ float wsb[32*49];
    __shared__ float ti[WY*WX];
    __shared__ float te[WY*WX];
    const int tid = threadIdx.x;
    const int tile = blockIdx.x;          // 0..31
    const int cch  = blockIdx.y*32;       // ci chunk base
    const int b    = blockIdx.z;
    for (int i = tid; i < 32*49; i += 128) { wsa[i] = aw[cch*49 + i]; wsb[i] = au[cch*49 + i]; }
    const int y0 = (tile >> 2)*8, x0 = (tile & 3)*16;
    const int tx = tid & 15, ty = tid >> 4;   // ty 0..7
    const float* ib = input_ + (size_t)b*Cc*HWc;
    const float* eb = exc    + (size_t)b*Cc*HWc;
    float acc = 0.f;
    for (int ci = 0; ci < 32; ++ci) {
        __syncthreads();
        for (int i = tid; i < WY*WX; i += 128) {
            int iy = i / WX, ix = i - iy*WX;
            int gy = y0 + iy - PADc, gx = x0 + ix - PADc;
            float v0 = 0.f, v1 = 0.f;
            if (gy >= 0 && gy < Hc && gx >= 0 && gx < Wc) {
                size_t o = (size_t)(cch+ci)*HWc + gy*Wc + gx;
                v0 = ib[o]; v1 = eb[o];
            }
            ti[i] = v0; te[i] = v1;
        }
        __syncthreads();
        const float* wa = &wsa[ci*49];
        const float* wb = &wsb[ci*49];
        #pragma unroll
        for (int kh = 0; kh < 7; ++kh) {
            #pragma unroll
            for (int kw = 0; kw < 7; ++kw) {
                const int k = kh*7+kw;
                acc += ti[(ty+kh)*WX + tx+kw] * wa[k];
                acc += te[(ty+kh)*WX + tx+kw] * wb[k];
            }
        }
    }
    atomicAdd(&att[(size_t)b*HWc + (size_t)(y0+ty)*Wc + (x0+tx)], acc);
}

__global__ __launch_bounds__(256) void att_final(
    float* __restrict__ att, const float* __restrict__ awb, const float* __restrict__ aub)
{
    int i = blockIdx.x*256 + threadIdx.x;
    float z = att[i] + awb[0] + aub[0];
    att[i] = 1.f/(1.f+expf(-z));
}

// ---------------------------------------------------------------------------
// conv7 via MFMA implicit GEMM.
// A = weights (M=co=128) loaded DIRECTLY FROM GLOBAL (L1/L2-resident,
// 1.6 MB shared by all blocks) -> no weight LDS, no main-loop barriers.
// B = activations (N=px=128: 8 rows x 16 cols) staged once in swizzled LDS.
// 4 waves (2 co-halves x 2 px-halves), wave tile 64co x 64px = 2x2 MFMA 32x32.
// grid = (4 x-tiles, 8 y-tiles, B) = 256 blocks, 256 threads.
// ---------------------------------------------------------------------------
__global__ __launch_bounds__(256) void conv7_mfma(
    const float* __restrict__ x, const float* __restrict__ att,
    const f16* __restrict__ wt, float* __restrict__ out)
{
    __shared__ unsigned char smem[ALDS_BYTES];
    const int tid = threadIdx.x;
    const int x0 = blockIdx.x * PX;
    const int y0 = blockIdx.y * PY;
    const int b  = blockIdx.z;
    const float* xb = x + (size_t)b*Cc*HWc;

    // ---- stage activations: [pos][ci] f16, slot-swizzled ----
    for (int idx = tid; idx < NPOS*16; idx += 256) {
        int slot = idx / NPOS;            // 16B slot = 8 ci
        int pos  = idx - slot*NPOS;
        int r = pos / WX, xw = pos - r*WX;
        int gy = y0 + r - PADc, gx = x0 + xw - PADc;
        bool inb = (gy >= 0 && gy < Hc && gx >= 0 && gx < Wc);
        float g = 1.f;
        if (att) g = inb ? att[(size_t)b*HWc + gy*Wc + gx] : 0.f;
        unsigned int pk[4];
        #pragma unroll
        for (int jj = 0; jj < 4; ++jj) {
            float v0 = 0.f, v1 = 0.f;
            if (inb) {
                size_t o = (size_t)(slot*8 + jj*2)*HWc + (size_t)gy*Wc + gx;
                v0 = xb[o]; v1 = xb[o + HWc];
            }
            f16 h0 = (f16)(v0*g), h1 = (f16)(v1*g);
            unsigned short u0 = __builtin_bit_cast(unsigned short, h0);
            unsigned short u1 = __builtin_bit_cast(unsigned short, h1);
            pk[jj] = (unsigned int)u0 | ((unsigned int)u1 << 16);
        }
        *(uint4*)(smem + pos*AROW + ((slot ^ (pos & 15)) << 4)) =
            make_uint4(pk[0], pk[1], pk[2], pk[3]);
    }
    __syncthreads();

    const int l   = tid & 63;
    const int wid = tid >> 6;
    const int wco = (wid >> 1) << 6;       // 0 / 64
    const int wpy = (wid & 1) << 2;        // 0 / 4
    const int lr  = l & 31;
    const int hi  = l >> 5;                // 0/1
    const int yA  = wpy + (lr >> 4);       // local row for nt=0
    const int xA  = lr & 15;

    f32x16 acc00 = {}, acc01 = {}, acc10 = {}, acc11 = {};

    // per-lane global weight row bases (co rows, f16 elements)
    const f16* wrow0 = wt + (size_t)(wco      + lr)*Cc + hi*8;
    const f16* wrow1 = wt + (size_t)(wco + 32 + lr)*Cc + hi*8;

    for (int t = 0; t < TAPS; ++t) {
        const int kh = t / 7, kw = t - kh*7;
        const int pos0 = (yA + kh)*WX + xA + kw;
        const int pos1 = pos0 + 2*WX;
        const size_t tapoff = (size_t)t*Cc*Cc;
        #pragma unroll
        for (int s = 0; s < 8; ++s) {
            const int slot = (s << 1) + hi;
            f16x8 a0 = *(const f16x8*)(wrow0 + tapoff + s*16);
            f16x8 a1 = *(const f16x8*)(wrow1 + tapoff + s*16);
            f16x8 b0 = *(const f16x8*)(smem + pos0*AROW + ((slot ^ (pos0 & 15)) << 4));
            f16x8 b1 = *(const f16x8*)(smem + pos1*AROW + ((slot ^ (pos1 & 15)) << 4));
            acc00 = __builtin_amdgcn_mfma_f32_32x32x16_f16(a0, b0, acc00, 0, 0, 0);
            acc01 = __builtin_amdgcn_mfma_f32_32x32x16_f16(a0, b1, acc01, 0, 0, 0);
            acc10 = __builtin_amdgcn_mfma_f32_32x32x16_f16(a1, b0, acc10, 0, 0, 0);
            acc11 = __builtin_amdgcn_mfma_f32_32x32x16_f16(a1, b1, acc11, 0, 0, 0);
        }
    }

    // ---- epilogue: C row = co, col = px ----
    const int xg = x0 + xA;
    #pragma unroll
    for (int r = 0; r < 16; ++r) {
        const int cr = (r & 3) + 8*(r >> 2) + 4*hi;
        const int y00 = y0 + wpy + 0 + (lr >> 4);
        const int y01 = y0 + wpy + 2 + (lr >> 4);
        out[((size_t)b*Cc + wco      + cr)*HWc + (size_t)y00*Wc + xg] = acc00[r];
        out[((size_t)b*Cc + wco      + cr)*HWc + (size_t)y01*Wc + xg] = acc01[r];
        out[((size_t)b*Cc + wco + 32 + cr)*HWc + (size_t)y00*Wc + xg] = acc10[r];
        out[((size_t)b*Cc + wco + 32 + cr)*HWc + (size_t)y01*Wc + xg] = acc11[r];
    }
}

// ---------------------------------------------------------------------------
// BN stats -> per-channel scale/bias
// ---------------------------------------------------------------------------
__global__ __launch_bounds__(256) void bn_stats_kernel(
    const float* __restrict__ x, const float* __restrict__ g,
    const float* __restrict__ bta, float* __restrict__ sc, float* __restrict__ bi)
{
    const int c = blockIdx.x;
    const int tid = threadIdx.x;
    float s = 0.f, s2 = 0.f;
    for (int i = tid; i < Bc*HWc; i += 256) {
        int b = i >> 12;
        int p = i & (HWc-1);
        float v = x[((size_t)b*Cc + c)*HWc + p];
        s += v; s2 += v*v;
    }
    #pragma unroll
    for (int off = 32; off > 0; off >>= 1) {
        s  += __shfl_down(s,  off);
        s2 += __shfl_down(s2, off);
    }
    __shared__ float ls[4], ls2[4];
    const int wv = tid >> 6;
    if ((tid & 63) == 0) { ls[wv] = s; ls2[wv] = s2; }
    __syncthreads();
    if (tid == 0) {
        s  = ls[0]+ls[1]+ls[2]+ls[3];
        s2 = ls2[0]+ls2[1]+ls2[2]+ls2[3];
        const float n = (float)(Bc*HWc);
        float m   = s / n;
        float var = s2 / n - m*m;
        float r   = rsqrtf(var + 1e-3f);
        float scale = r * g[c];
        sc[c] = scale;
        bi[c] = bta[c] - m*scale;
    }
}

// ---------------------------------------------------------------------------
// i-gate 1x1 convs + inhibition_hat + state update (fused)
// ---------------------------------------------------------------------------
#define GCO 32

__global__ __launch_bounds__(256) void gate_i_kernel(
    const float* __restrict__ input_, const float* __restrict__ inh,
    const float* __restrict__ iw, const float* __restrict__ iwb,
    const float* __restrict__ uw, const float* __restrict__ uwb,
    const float* c1, const float* __restrict__ sc, const float* __restrict__ bi,
    const float* __restrict__ att,
    const float* __restrict__ alpha, const float* __restrict__ mu,
    float* out)
{
    __shared__ float swi[Cc][GCO];
    __shared__ float swu[Cc][GCO];
    const int tid = threadIdx.x;
    const int p0  = blockIdx.x * 256;
    const int cob = blockIdx.y * GCO;
    const int b   = blockIdx.z;
    for (int i = tid; i < Cc*GCO; i += 256) {
        int ci = i / GCO, co = i % GCO;
        swi[ci][co] = iw[(size_t)(cob+co)*Cc + ci];
        swu[ci][co] = uw[(size_t)(cob+co)*Cc + ci];
    }
    __syncthreads();
    const int p = p0 + tid;
    const float* xb = input_ + (size_t)b*Cc*HWc + p;
    const float* hb = inh    + (size_t)b*Cc*HWc + p;
    float acc[GCO];
    #pragma unroll
    for (int i = 0; i < GCO; ++i) acc[i] = 0.f;
    #pragma unroll 4
    for (int ci = 0; ci < Cc; ++ci) {
        float xi = xb[(size_t)ci*HWc];
        float xu = hb[(size_t)ci*HWc];
        #pragma unroll
        for (int co = 0; co < GCO; ++co)
            acc[co] += xi*swi[ci][co] + xu*swu[ci][co];
    }
    const float a = att[(size_t)b*HWc + p];
    #pragma unroll
    for (int co = 0; co < GCO; ++co) {
        const int c = cob + co;
        float hv = hb[(size_t)c*HWc];
        float g  = 1.f/(1.f+expf(-(acc[co] + iwb[c] + uwb[c])));
        size_t idx = ((size_t)b*Cc + c)*HWc + p;
        float intx = c1[idx]*sc[c] + bi[c];
        float gi = xb[(size_t)c*HWc] * a;
        float gh = hv * a;
        float ihat = tanhf(gi - tanhf(intx*(alpha[c]*gh + mu[c])));
        out[idx] = (1.f-g)*hv + g*ihat;
    }
}

// ---------------------------------------------------------------------------
// e-gate 1x1 convs + excitation_hat + state update (fused)
// ---------------------------------------------------------------------------
__global__ __launch_bounds__(256) void gate_e_kernel(
    const float* __restrict__ inh_new, const float* __restrict__ exc,
    const float* __restrict__ ew, const float* __restrict__ ewb,
    const float* __restrict__ uw, const float* __restrict__ uwb,
    const float* c2, const float* __restrict__ sc, const float* __restrict__ bi,
    const float* __restrict__ kappa, const float* __restrict__ gamma_,
    const float* __restrict__ wp,
    float* out)
{
    __shared__ float swe[Cc][GCO];
    __shared__ float swu[Cc][GCO];
    const int tid = threadIdx.x;
    const int p0  = blockIdx.x * 256;
    const int cob = blockIdx.y * GCO;
    const int b   = blockIdx.z;
    for (int i = tid; i < Cc*GCO; i += 256) {
        int ci = i / GCO, co = i % GCO;
        swe[ci][co] = ew[(size_t)(cob+co)*Cc + ci];
        swu[ci][co] = uw[(size_t)(cob+co)*Cc + ci];
    }
    __syncthreads();
    const int p = p0 + tid;
    const float* hb = inh_new + (size_t)b*Cc*HWc + p;
    const float* eb = exc     + (size_t)b*Cc*HWc + p;
    float acc[GCO];
    #pragma unroll
    for (int i = 0; i < GCO; ++i) acc[i] = 0.f;
    #pragma unroll 4
    for (int ci = 0; ci < Cc; ++ci) {
        float xi = hb[(size_t)ci*HWc];
        float xu = eb[(size_t)ci*HWc];
        #pragma unroll
        for (int co = 0; co < GCO; ++co)
            acc[co] += xi*swe[ci][co] + xu*swu[ci][co];
    }
    #pragma unroll
    for (int co = 0; co < GCO; ++co) {
        const int c = cob + co;
        float hv = hb[(size_t)c*HWc];
        float ev = eb[(size_t)c*HWc];
        float g  = 1.f/(1.f+expf(-(acc[co] + ewb[c] + uwb[c])));
        size_t idx = ((size_t)b*Cc + c)*HWc + p;
        float intx = c2[idx]*sc[c] + bi[c];
        float ehat = tanhf(kappa[c]*hv + gamma_[c]*intx + wp[c]*hv*intx);
        out[idx] = (1.f-g)*ev + g*ehat;
    }
}

// ---------------------------------------------------------------------------
extern "C" void kernel_launch(void* const* d_in, const int* in_sizes, int n_in,
                              void* d_out, int out_size, void* d_ws, size_t ws_size,
                              hipStream_t stream)
{
    (void)in_sizes; (void)n_in; (void)out_size; (void)ws_size;
    const float* input_ = (const float*)d_in[0];
    const float* inh    = (const float*)d_in[1];
    const float* exc    = (const float*)d_in[2];
    const float* a_w_w  = (const float*)d_in[3];
    const float* a_w_b  = (const float*)d_in[4];
    const float* a_u_w  = (const float*)d_in[5];
    const float* a_u_b  = (const float*)d_in[6];
    const float* i_w_w  = (const float*)d_in[7];
    const float* i_w_b  = (const float*)d_in[8];
    const float* i_u_w  = (const float*)d_in[9];
    const float* i_u_b  = (const float*)d_in[10];
    const float* e_w_w  = (const float*)d_in[11];
    const float* e_w_b  = (const float*)d_in[12];
    const float* e_u_w  = (const float*)d_in[13];
    const float* e_u_b  = (const float*)d_in[14];
    const float* w_inh  = (const float*)d_in[15];
    const float* w_exc  = (const float*)d_in[16];
    const float* alpha  = (const float*)d_in[17];
    const float* gamma_ = (const float*)d_in[18];
    const float* kappa  = (const float*)d_in[19];
    const float* w_par  = (const float*)d_in[20];
    const float* mu     = (const float*)d_in[21];
    const float* bn0_g  = (const float*)d_in[22];
    const float* bn0_b  = (const float*)d_in[23];
    const float* bn1_g  = (const float*)d_in[24];
    const float* bn1_b  = (const float*)d_in[25];

    float* out = (float*)d_out;
    const size_t N = (size_t)Bc*Cc*HWc;
    float* c1 = out;
    float* c2 = out + N;

    float* att = (float*)d_ws;               // 32768 floats
    float* sc0 = att + 32768;
    float* bi0 = sc0 + Cc;
    float* sc1 = bi0 + Cc;
    float* bi1 = sc1 + Cc;
    f16* wt1 = (f16*)((char*)d_ws + 33280u*4u);       // 802816 f16
    f16* wt2 = wt1 + (size_t)TAPS*Cc*Cc;

    // 0. weight transpose (f16) + zero att
    prep_kernel<<<(TAPS*Cc*Cc + 255)/256, 256, 0, stream>>>(w_inh, w_exc, wt1, wt2, att);
    // 1. attention gate (ci-split partials + finalize)
    att_partial<<<dim3(32, 4, Bc), 128, 0, stream>>>(input_, exc, a_w_w, a_u_w, att);
    att_final<<<(Bc*HWc)/256, 256, 0, stream>>>(att, a_w_b, a_u_b);
    // 2. conv(exc * att, w_inh) -> c1  (MFMA)
    conv7_mfma<<<dim3(4, 8, Bc), 256, 0, stream>>>(exc, att, wt1, c1);
    // 3. BN stats for c1
    bn_stats_kernel<<<Cc, 256, 0, stream>>>(c1, bn0_g, bn0_b, sc0, bi0);
    // 4. i-gate + inhibition_hat + update -> inhibition_new (in place over c1)
    gate_i_kernel<<<dim3(HWc/256, Cc/GCO, Bc), 256, 0, stream>>>(
        input_, inh, i_w_w, i_w_b, i_u_w, i_u_b, c1, sc0, bi0, att, alpha, mu, out);
    // 5. conv(inhibition_new, w_exc) -> c2  (MFMA)
    conv7_mfma<<<dim3(4, 8, Bc), 256, 0, stream>>>(out, nullptr, wt2, c2);
    // 6. BN stats for c2
    bn_stats_kernel<<<Cc, 256, 0, stream>>>(c2, bn1_g, bn1_b, sc1, bi1);
    // 7. e-gate + excitation_hat + update -> excitation_new (in place over c2)
    gate_e_kernel<<<dim3(HWc/256, Cc/GCO, Bc), 256, 0, stream>>>(
        out, exc, e_w_w, e_w_b, e_u_w, e_u_b, c2, sc1, bi1, kappa, gamma_, w_par, out + N);
}

// Round 10
// 640.837 us; speedup vs baseline: 3.6310x; 1.2275x over previous
//
#include <hip/hip_runtime.h>
#include <cstddef>

typedef _Float16 f16;
typedef _Float16 f16x8 __attribute__((ext_vector_type(8)));
typedef float f32x16 __attribute__((ext_vector_type(16)));

#define Bc   8
#define Cc   128
#define Hc   64
#define Wc   64
#define HWc  4096
#define PADc 3
#define TAPS 49

// ---------------- conv7 MFMA geometry ----------------
#define PY 8            // output rows per workgroup
#define PX 16           // output cols per workgroup
#define WY 14           // input window rows  (PY+6)
#define WX 22           // input window cols  (PX+6)
#define NPOS (WY*WX)    // 308 staged positions
#define AROW 256        // bytes per position row (128 ci * 2B)
#define ALDS_BYTES (NPOS*AROW)        // 78848

// ---------------------------------------------------------------------------
// prep: transpose conv weights to [tap][co][ci] f16, build concatenated
// gate weights [co][k=256] f16 (k<128 -> W, k>=128 -> U), zero att buffer
// ---------------------------------------------------------------------------
__global__ __launch_bounds__(256) void prep_kernel(
    const float* __restrict__ w1, const float* __restrict__ w2,
    const float* __restrict__ iww, const float* __restrict__ iuw,
    const float* __restrict__ eww, const float* __restrict__ euw,
    f16* __restrict__ wt1, f16* __restrict__ wt2,
    f16* __restrict__ wgi, f16* __restrict__ wge,
    float* __restrict__ att)
{
    int idx = blockIdx.x*256 + threadIdx.x;
    const int NW = TAPS*Cc*Cc;
    if (idx < NW) {
        int tap = idx / (Cc*Cc);
        int rem = idx - tap*(Cc*Cc);
        int co = rem >> 7, ci = rem & 127;
        size_t src = (size_t)(co*Cc + ci)*TAPS + tap;
        wt1[idx] = (f16)w1[src];
        wt2[idx] = (f16)w2[src];
    }
    if (idx < 2*Cc*Cc) {           // 32768 gate-weight entries
        int co = idx >> 8, k = idx & 255;
        wgi[idx] = (f16)((k < 128) ? iww[co*Cc + k] : iuw[co*Cc + (k-128)]);
        wge[idx] = (f16)((k < 128) ? eww[co*Cc + k] : euw[co*Cc + (k-128)]);
    }
    if (idx < Bc*HWc) att[idx] = 0.f;
}

// ---------------------------------------------------------------------------
// attention gate, ci-split partial sums (atomicAdd), then sigmoid finalize
// ---------------------------------------------------------------------------
__global__ __launch_bounds__(128) void att_partial(
    const float* __restrict__ input_, const float* __restrict__ exc,
    const float* __restrict__ aw, const float* __restrict__ au,
    float* __restrict__ att)
{
    __shared__ float wsa[32*49];
    __shared__ float wsb[32*49];
    __shared__ float ti[WY*WX];
    __shared__ float te[WY*WX];
    const int tid = threadIdx.x;
    const int tile = blockIdx.x;          // 0..31
    const int cch  = blockIdx.y*32;       // ci chunk base
    const int b    = blockIdx.z;
    for (int i = tid; i < 32*49; i += 128) { wsa[i] = aw[cch*49 + i]; wsb[i] = au[cch*49 + i]; }
    const int y0 = (tile >> 2)*8, x0 = (tile & 3)*16;
    const int tx = tid & 15, ty = tid >> 4;   // ty 0..7
    const float* ib = input_ + (size_t)b*Cc*HWc;
    const float* eb = exc    + (size_t)b*Cc*HWc;
    float acc = 0.f;
    for (int ci = 0; ci < 32; ++ci) {
        __syncthreads();
        for (int i = tid; i < WY*WX; i += 128) {
            int iy = i / WX, ix = i - iy*WX;
            int gy = y0 + iy - PADc, gx = x0 + ix - PADc;
            float v0 = 0.f, v1 = 0.f;
            if (gy >= 0 && gy < Hc && gx >= 0 && gx < Wc) {
                size_t o = (size_t)(cch+ci)*HWc + gy*Wc + gx;
                v0 = ib[o]; v1 = eb[o];
            }
            ti[i] = v0; te[i] = v1;
        }
        __syncthreads();
        const float* wa = &wsa[ci*49];
        const float* wb = &wsb[ci*49];
        #pragma unroll
        for (int kh = 0; kh < 7; ++kh) {
            #pragma unroll
            for (int kw = 0; kw < 7; ++kw) {
                const int k = kh*7+kw;
                acc += ti[(ty+kh)*WX + tx+kw] * wa[k];
                acc += te[(ty+kh)*WX + tx+kw] * wb[k];
            }
        }
    }
    atomicAdd(&att[(size_t)b*HWc + (size_t)(y0+ty)*Wc + (x0+tx)], acc);
}

__global__ __launch_bounds__(256) void att_final(
    float* __restrict__ att, const float* __restrict__ awb, const float* __restrict__ aub)
{
    int i = blockIdx.x*256 + threadIdx.x;
    float z = att[i] + awb[0] + aub[0];
    att[i] = 1.f/(1.f+expf(-z));
}

// ---------------------------------------------------------------------------
// conv7 via MFMA implicit GEMM (unchanged from passing round-5 version)
// ---------------------------------------------------------------------------
__global__ __launch_bounds__(256) void conv7_mfma(
    const float* __restrict__ x, const float* __restrict__ att,
    const f16* __restrict__ wt, float* __restrict__ out)
{
    __shared__ unsigned char smem[ALDS_BYTES];
    const int tid = threadIdx.x;
    const int x0 = blockIdx.x * PX;
    const int y0 = blockIdx.y * PY;
    const int b  = blockIdx.z;
    const float* xb = x + (size_t)b*Cc*HWc;

    for (int idx = tid; idx < NPOS*16; idx += 256) {
        int slot = idx / NPOS;            // 16B slot = 8 ci
        int pos  = idx - slot*NPOS;
        int r = pos / WX, xw = pos - r*WX;
        int gy = y0 + r - PADc, gx = x0 + xw - PADc;
        bool inb = (gy >= 0 && gy < Hc && gx >= 0 && gx < Wc);
        float g = 1.f;
        if (att) g = inb ? att[(size_t)b*HWc + gy*Wc + gx] : 0.f;
        unsigned int pk[4];
        #pragma unroll
        for (int jj = 0; jj < 4; ++jj) {
            float v0 = 0.f, v1 = 0.f;
            if (inb) {
                size_t o = (size_t)(slot*8 + jj*2)*HWc + (size_t)gy*Wc + gx;
                v0 = xb[o]; v1 = xb[o + HWc];
            }
            f16 h0 = (f16)(v0*g), h1 = (f16)(v1*g);
            unsigned short u0 = __builtin_bit_cast(unsigned short, h0);
            unsigned short u1 = __builtin_bit_cast(unsigned short, h1);
            pk[jj] = (unsigned int)u0 | ((unsigned int)u1 << 16);
        }
        *(uint4*)(smem + pos*AROW + ((slot ^ (pos & 15)) << 4)) =
            make_uint4(pk[0], pk[1], pk[2], pk[3]);
    }
    __syncthreads();

    const int l   = tid & 63;
    const int wid = tid >> 6;
    const int wco = (wid >> 1) << 6;       // 0 / 64
    const int wpy = (wid & 1) << 2;        // 0 / 4
    const int lr  = l & 31;
    const int hi  = l >> 5;                // 0/1
    const int yA  = wpy + (lr >> 4);
    const int xA  = l & 15;

    f32x16 acc00 = {}, acc01 = {}, acc10 = {}, acc11 = {};

    const f16* wrow0 = wt + (size_t)(wco      + lr)*Cc + hi*8;
    const f16* wrow1 = wt + (size_t)(wco + 32 + lr)*Cc + hi*8;

    for (int t = 0; t < TAPS; ++t) {
        const int kh = t / 7, kw = t - kh*7;
        const int pos0 = (yA + kh)*WX + xA + kw;
        const int pos1 = pos0 + 2*WX;
        const size_t tapoff = (size_t)t*Cc*Cc;
        #pragma unroll
        for (int s = 0; s < 8; ++s) {
            const int slot = (s << 1) + hi;
            f16x8 a0 = *(const f16x8*)(wrow0 + tapoff + s*16);
            f16x8 a1 = *(const f16x8*)(wrow1 + tapoff + s*16);
            f16x8 b0 = *(const f16x8*)(smem + pos0*AROW + ((slot ^ (pos0 & 15)) << 4));
            f16x8 b1 = *(const f16x8*)(smem + pos1*AROW + ((slot ^ (pos1 & 15)) << 4));
            acc00 = __builtin_amdgcn_mfma_f32_32x32x16_f16(a0, b0, acc00, 0, 0, 0);
            acc01 = __builtin_amdgcn_mfma_f32_32x32x16_f16(a0, b1, acc01, 0, 0, 0);
            acc10 = __builtin_amdgcn_mfma_f32_32x32x16_f16(a1, b0, acc10, 0, 0, 0);
            acc11 = __builtin_amdgcn_mfma_f32_32x32x16_f16(a1, b1, acc11, 0, 0, 0);
        }
    }

    const int xg = x0 + xA;
    #pragma unroll
    for (int r = 0; r < 16; ++r) {
        const int cr = (r & 3) + 8*(r >> 2) + 4*hi;
        const int y00 = y0 + wpy + 0 + (lr >> 4);
        const int y01 = y0 + wpy + 2 + (lr >> 4);
        out[((size_t)b*Cc + wco      + cr)*HWc + (size_t)y00*Wc + xg] = acc00[r];
        out[((size_t)b*Cc + wco      + cr)*HWc + (size_t)y01*Wc + xg] = acc01[r];
        out[((size_t)b*Cc + wco + 32 + cr)*HWc + (size_t)y00*Wc + xg] = acc10[r];
        out[((size_t)b*Cc + wco + 32 + cr)*HWc + (size_t)y01*Wc + xg] = acc11[r];
    }
}

// ---------------------------------------------------------------------------
// BN stats -> per-channel scale/bias
// ---------------------------------------------------------------------------
__global__ __launch_bounds__(256) void bn_stats_kernel(
    const float* __restrict__ x, const float* __restrict__ g,
    const float* __restrict__ bta, float* __restrict__ sc, float* __restrict__ bi)
{
    const int c = blockIdx.x;
    const int tid = threadIdx.x;
    float s = 0.f, s2 = 0.f;
    for (int i = tid; i < Bc*HWc; i += 256) {
        int b = i >> 12;
        int p = i & (HWc-1);
        float v = x[((size_t)b*Cc + c)*HWc + p];
        s += v; s2 += v*v;
    }
    #pragma unroll
    for (int off = 32; off > 0; off >>= 1) {
        s  += __shfl_down(s,  off);
        s2 += __shfl_down(s2, off);
    }
    __shared__ float ls[4], ls2[4];
    const int wv = tid >> 6;
    if ((tid & 63) == 0) { ls[wv] = s; ls2[wv] = s2; }
    __syncthreads();
    if (tid == 0) {
        s  = ls[0]+ls[1]+ls[2]+ls[3];
        s2 = ls2[0]+ls2[1]+ls2[2]+ls2[3];
        const float n = (float)(Bc*HWc);
        float m   = s / n;
        float var = s2 / n - m*m;
        float r   = rsqrtf(var + 1e-3f);
        float scale = r * g[c];
        sc[c] = scale;
        bi[c] = bta[c] - m*scale;
    }
}

// ---------------------------------------------------------------------------
// gate_i via MFMA: z[co][p] = sum_k wgi[co][k] * cat(x,h)[k][p], then fused
// sigmoid/tanh/BN epilogue.  Block: 128 co x 128 px, 4 waves, K=256.
// grid = (HW/128, B) = 256 blocks.
// ---------------------------------------------------------------------------
__global__ __launch_bounds__(256) void gate_i_mfma(
    const float* __restrict__ input_, const float* __restrict__ inh,
    const f16* __restrict__ wg,
    const float* __restrict__ iwb, const float* __restrict__ uwb,
    const float* c1, const float* __restrict__ sc, const float* __restrict__ bi,
    const float* __restrict__ att,
    const float* __restrict__ alpha, const float* __restrict__ mu,
    float* out)
{
    __shared__ unsigned char bsm[128*512];   // [px][32 slots of 16B, swizzled]
    __shared__ float sbias[Cc], ssc[Cc], sbi[Cc], sal[Cc], smu[Cc];
    const int tid = threadIdx.x;
    const int p0 = blockIdx.x * 128;
    const int b  = blockIdx.y;
    if (tid < Cc) {
        sbias[tid] = iwb[tid] + uwb[tid];
        ssc[tid] = sc[tid]; sbi[tid] = bi[tid];
        sal[tid] = alpha[tid]; smu[tid] = mu[tid];
    }
    const float* xb = input_ + (size_t)b*Cc*HWc + p0;
    const float* hb = inh    + (size_t)b*Cc*HWc + p0;
    #pragma unroll
    for (int it = 0; it < 16; ++it) {
        int idx = tid + it*256;
        int px = idx & 127, slot = idx >> 7;
        const float* src = (slot < 16) ? (xb + (size_t)(slot*8)*HWc)
                                       : (hb + (size_t)((slot-16)*8)*HWc);
        unsigned int pk[4];
        #pragma unroll
        for (int jj = 0; jj < 4; ++jj) {
            f16 h0 = (f16)src[(size_t)(jj*2  )*HWc + px];
            f16 h1 = (f16)src[(size_t)(jj*2+1)*HWc + px];
            pk[jj] = (unsigned)__builtin_bit_cast(unsigned short, h0)
                   | ((unsigned)__builtin_bit_cast(unsigned short, h1) << 16);
        }
        *(uint4*)(bsm + px*512 + ((slot ^ (px & 31)) << 4)) =
            make_uint4(pk[0], pk[1], pk[2], pk[3]);
    }
    __syncthreads();

    const int l   = tid & 63;
    const int wid = tid >> 6;
    const int wco = (wid >> 1) << 6;
    const int wpx = (wid & 1) << 6;
    const int lr  = l & 31;
    const int hi  = l >> 5;

    f32x16 acc00 = {}, acc01 = {}, acc10 = {}, acc11 = {};
    const f16* wr0 = wg + (size_t)(wco      + lr)*256 + hi*8;
    const f16* wr1 = wg + (size_t)(wco + 32 + lr)*256 + hi*8;
    const unsigned char* br0 = bsm + (size_t)(wpx      + lr)*512;
    const unsigned char* br1 = bsm + (size_t)(wpx + 32 + lr)*512;
    #pragma unroll
    for (int s = 0; s < 16; ++s) {
        const int slot = 2*s + hi;
        const int swz = (slot ^ lr) << 4;       // (px&31)==lr for both tiles
        f16x8 a0 = *(const f16x8*)(wr0 + s*16);
        f16x8 a1 = *(const f16x8*)(wr1 + s*16);
        f16x8 b0 = *(const f16x8*)(br0 + swz);
        f16x8 b1 = *(const f16x8*)(br1 + swz);
        acc00 = __builtin_amdgcn_mfma_f32_32x32x16_f16(a0, b0, acc00, 0, 0, 0);
        acc01 = __builtin_amdgcn_mfma_f32_32x32x16_f16(a0, b1, acc01, 0, 0, 0);
        acc10 = __builtin_amdgcn_mfma_f32_32x32x16_f16(a1, b0, acc10, 0, 0, 0);
        acc11 = __builtin_amdgcn_mfma_f32_32x32x16_f16(a1, b1, acc11, 0, 0, 0);
    }

    const int pA = p0 + wpx + lr;
    const int pB = pA + 32;
    const float aA = att[(size_t)b*HWc + pA];
    const float aB = att[(size_t)b*HWc + pB];
    #pragma unroll
    for (int r = 0; r < 16; ++r) {
        const int cr = (r & 3) + 8*(r >> 2) + 4*hi;
        const int c0 = wco + cr, c1i = wco + 32 + cr;
        const float bz0 = sbias[c0], bz1 = sbias[c1i];
        const float sc0v = ssc[c0], sc1v = ssc[c1i];
        const float bi0v = sbi[c0], bi1v = sbi[c1i];
        const float al0 = sal[c0], al1 = sal[c1i];
        const float mu0 = smu[c0], mu1 = smu[c1i];
        #pragma unroll
        for (int q = 0; q < 4; ++q) {
            const int cc = (q < 2) ? c0 : c1i;
            const int pp = (q & 1) ? pB : pA;
            const float av = (q & 1) ? aB : aA;
            const float z = (q==0)?acc00[r]:(q==1)?acc01[r]:(q==2)?acc10[r]:acc11[r];
            const float bz = (q < 2) ? bz0 : bz1;
            const float scv = (q < 2) ? sc0v : sc1v;
            const float biv = (q < 2) ? bi0v : bi1v;
            const float alv = (q < 2) ? al0 : al1;
            const float muv = (q < 2) ? mu0 : mu1;
            size_t idx = ((size_t)b*Cc + cc)*HWc + pp;
            float hv = inh[idx];
            float xi = input_[idx];
            float intx = c1[idx]*scv + biv;
            float g = 1.f/(1.f+expf(-(z + bz)));
            float ihat = tanhf(xi*av - tanhf(intx*(alv*(hv*av) + muv)));
            out[idx] = (1.f-g)*hv + g*ihat;
        }
    }
}

// ---------------------------------------------------------------------------
// gate_e via MFMA: K-concat = [inh_new ; exc].
// ---------------------------------------------------------------------------
__global__ __launch_bounds__(256) void gate_e_mfma(
    const float* __restrict__ hnew, const float* __restrict__ exc,
    const f16* __restrict__ wg,
    const float* __restrict__ ewb, const float* __restrict__ uwb,
    const float* c2, const float* __restrict__ sc, const float* __restrict__ bi,
    const float* __restrict__ kappa, const float* __restrict__ gamma_,
    const float* __restrict__ wp,
    float* out)
{
    __shared__ unsigned char bsm[128*512];
    __shared__ float sbias[Cc], ssc[Cc], sbi[Cc], skp[Cc], sgm[Cc], swp[Cc];
    const int tid = threadIdx.x;
    const int p0 = blockIdx.x * 128;
    const int b  = blockIdx.y;
    if (tid < Cc) {
        sbias[tid] = ewb[tid] + uwb[tid];
        ssc[tid] = sc[tid]; sbi[tid] = bi[tid];
        skp[tid] = kappa[tid]; sgm[tid] = gamma_[tid]; swp[tid] = wp[tid];
    }
    const float* xb = hnew + (size_t)b*Cc*HWc + p0;
    const float* eb = exc  + (size_t)b*Cc*HWc + p0;
    #pragma unroll
    for (int it = 0; it < 16; ++it) {
        int idx = tid + it*256;
        int px = idx & 127, slot = idx >> 7;
        const float* src = (slot < 16) ? (xb + (size_t)(slot*8)*HWc)
                                       : (eb + (size_t)((slot-16)*8)*HWc);
        unsigned int pk[4];
        #pragma unroll
        for (int jj = 0; jj < 4; ++jj) {
            f16 h0 = (f16)src[(size_t)(jj*2  )*HWc + px];
            f16 h1 = (f16)src[(size_t)(jj*2+1)*HWc + px];
            pk[jj] = (unsigned)__builtin_bit_cast(unsigned short, h0)
                   | ((unsigned)__builtin_bit_cast(unsigned short, h1) << 16);
        }
        *(uint4*)(bsm + px*512 + ((slot ^ (px & 31)) << 4)) =
            make_uint4(pk[0], pk[1], pk[2], pk[3]);
    }
    __syncthreads();

    const int l   = tid & 63;
    const int wid = tid >> 6;
    const int wco = (wid >> 1) << 6;
    const int wpx = (wid & 1) << 6;
    const int lr  = l & 31;
    const int hi  = l >> 5;

    f32x16 acc00 = {}, acc01 = {}, acc10 = {}, acc11 = {};
    const f16* wr0 = wg + (size_t)(wco      + lr)*256 + hi*8;
    const f16* wr1 = wg + (size_t)(wco + 32 + lr)*256 + hi*8;
    const unsigned char* br0 = bsm + (size_t)(wpx      + lr)*512;
    const unsigned char* br1 = bsm + (size_t)(wpx + 32 + lr)*512;
    #pragma unroll
    for (int s = 0; s < 16; ++s) {
        const int slot = 2*s + hi;
        const int swz = (slot ^ lr) << 4;
        f16x8 a0 = *(const f16x8*)(wr0 + s*16);
        f16x8 a1 = *(const f16x8*)(wr1 + s*16);
        f16x8 b0 = *(const f16x8*)(br0 + swz);
        f16x8 b1 = *(const f16x8*)(br1 + swz);
        acc00 = __builtin_amdgcn_mfma_f32_32x32x16_f16(a0, b0, acc00, 0, 0, 0);
        acc01 = __builtin_amdgcn_mfma_f32_32x32x16_f16(a0, b1, acc01, 0, 0, 0);
        acc10 = __builtin_amdgcn_mfma_f32_32x32x16_f16(a1, b0, acc10, 0, 0, 0);
        acc11 = __builtin_amdgcn_mfma_f32_32x32x16_f16(a1, b1, acc11, 0, 0, 0);
    }

    const int pA = p0 + wpx + lr;
    const int pB = pA + 32;
    #pragma unroll
    for (int r = 0; r < 16; ++r) {
        const int cr = (r & 3) + 8*(r >> 2) + 4*hi;
        const int c0 = wco + cr, c1i = wco + 32 + cr;
        #pragma unroll
        for (int q = 0; q < 4; ++q) {
            const int cc = (q < 2) ? c0 : c1i;
            const int pp = (q & 1) ? pB : pA;
            const float z = (q==0)?acc00[r]:(q==1)?acc01[r]:(q==2)?acc10[r]:acc11[r];
            size_t idx = ((size_t)b*Cc + cc)*HWc + pp;
            float hv = hnew[idx];
            float ev = exc[idx];
            float intx = c2[idx]*ssc[cc] + sbi[cc];
            float g = 1.f/(1.f+expf(-(z + sbias[cc])));
            float ehat = tanhf(skp[cc]*hv + sgm[cc]*intx + swp[cc]*hv*intx);
            out[idx] = (1.f-g)*ev + g*ehat;
        }
    }
}

// ---------------------------------------------------------------------------
extern "C" void kernel_launch(void* const* d_in, const int* in_sizes, int n_in,
                              void* d_out, int out_size, void* d_ws, size_t ws_size,
                              hipStream_t stream)
{
    (void)in_sizes; (void)n_in; (void)out_size; (void)ws_size;
    const float* input_ = (const float*)d_in[0];
    const float* inh    = (const float*)d_in[1];
    const float* exc    = (const float*)d_in[2];
    const float* a_w_w  = (const float*)d_in[3];
    const float* a_w_b  = (const float*)d_in[4];
    const float* a_u_w  = (const float*)d_in[5];
    const float* a_u_b  = (const float*)d_in[6];
    const float* i_w_w  = (const float*)d_in[7];
    const float* i_w_b  = (const float*)d_in[8];
    const float* i_u_w  = (const float*)d_in[9];
    const float* i_u_b  = (const float*)d_in[10];
    const float* e_w_w  = (const float*)d_in[11];
    const float* e_w_b  = (const float*)d_in[12];
    const float* e_u_w  = (const float*)d_in[13];
    const float* e_u_b  = (const float*)d_in[14];
    const float* w_inh  = (const float*)d_in[15];
    const float* w_exc  = (const float*)d_in[16];
    const float* alpha  = (const float*)d_in[17];
    const float* gamma_ = (const float*)d_in[18];
    const float* kappa  = (const float*)d_in[19];
    const float* w_par  = (const float*)d_in[20];
    const float* mu     = (const float*)d_in[21];
    const float* bn0_g  = (const float*)d_in[22];
    const float* bn0_b  = (const float*)d_in[23];
    const float* bn1_g  = (const float*)d_in[24];
    const float* bn1_b  = (const float*)d_in[25];

    float* out = (float*)d_out;
    const size_t N = (size_t)Bc*Cc*HWc;
    float* c1 = out;
    float* c2 = out + N;

    float* att = (float*)d_ws;               // 32768 floats
    float* sc0 = att + 32768;
    float* bi0 = sc0 + Cc;
    float* sc1 = bi0 + Cc;
    float* bi1 = sc1 + Cc;
    f16* wt1 = (f16*)((char*)d_ws + 33280u*4u);        // 802816 f16
    f16* wt2 = wt1 + (size_t)TAPS*Cc*Cc;
    f16* wgi = wt2 + (size_t)TAPS*Cc*Cc;               // 32768 f16
    f16* wge = wgi + 2*Cc*Cc;

    // 0. weight transposes (f16) + zero att
    prep_kernel<<<(TAPS*Cc*Cc + 255)/256, 256, 0, stream>>>(
        w_inh, w_exc, i_w_w, i_u_w, e_w_w, e_u_w, wt1, wt2, wgi, wge, att);
    // 1. attention gate (ci-split partials + finalize)
    att_partial<<<dim3(32, 4, Bc), 128, 0, stream>>>(input_, exc, a_w_w, a_u_w, att);
    att_final<<<(Bc*HWc)/256, 256, 0, stream>>>(att, a_w_b, a_u_b);
    // 2. conv(exc * att, w_inh) -> c1  (MFMA)
    conv7_mfma<<<dim3(4, 8, Bc), 256, 0, stream>>>(exc, att, wt1, c1);
    // 3. BN stats for c1
    bn_stats_kernel<<<Cc, 256, 0, stream>>>(c1, bn0_g, bn0_b, sc0, bi0);
    // 4. i-gate GEMM + inhibition_hat + update (in place over c1)
    gate_i_mfma<<<dim3(HWc/128, Bc), 256, 0, stream>>>(
        input_, inh, wgi, i_w_b, i_u_b, c1, sc0, bi0, att, alpha, mu, out);
    // 5. conv(inhibition_new, w_exc) -> c2  (MFMA)
    conv7_mfma<<<dim3(4, 8, Bc), 256, 0, stream>>>(out, nullptr, wt2, c2);
    // 6. BN stats for c2
    bn_stats_kernel<<<Cc, 256, 0, stream>>>(c2, bn1_g, bn1_b, sc1, bi1);
    // 7. e-gate GEMM + excitation_hat + update (in place over c2)
    gate_e_mfma<<<dim3(HWc/128, Bc), 256, 0, stream>>>(
        out, exc, wge, e_w_b, e_u_b, c2, sc1, bi1, kappa, gamma_, w_par, out + N);
}